// Round 7
// baseline (610.000 us; speedup 1.0000x reference)
//
#include <hip/hip_runtime.h>

// Problem constants (fixed by reference setup_inputs)
#define BB 2
#define LQ 2048
#define SK 2048
#define CH 1024
#define NH 16
#define HD 64
#define GK 2048          // packed complex K (= 2*CH)
#define MM 4096          // B*L = B*S
#define ATT_SCALE 0.125f // 1/sqrt(64)

typedef _Float16 f16x8 __attribute__((ext_vector_type(8)));
typedef float f32x4 __attribute__((ext_vector_type(4)));
typedef unsigned short u16x8 __attribute__((ext_vector_type(8)));

__device__ __forceinline__ unsigned short h2u(_Float16 h) {
    union { _Float16 h; unsigned short u; } v; v.h = h; return v.u;
}
__device__ __forceinline__ void gload16(const _Float16* g, unsigned short* l) {
    __builtin_amdgcn_global_load_lds(
        (const __attribute__((address_space(1))) void*)g,
        (__attribute__((address_space(3))) void*)l, 16, 0, 0);
}

// 16-lane all-reduce max via DPP (full-rate VALU, no LDS pipe).
__device__ __forceinline__ float dpp_max16(float x) {
    union { float f; int i; } v, r;
    v.f = x;
    r.i = __builtin_amdgcn_update_dpp(v.i, v.i, 0xB1, 0xF, 0xF, false);  // quad_perm [1,0,3,2]
    v.f = fmaxf(v.f, r.f);
    r.i = __builtin_amdgcn_update_dpp(v.i, v.i, 0x4E, 0xF, 0xF, false);  // quad_perm [2,3,0,1]
    v.f = fmaxf(v.f, r.f);
    r.i = __builtin_amdgcn_update_dpp(v.i, v.i, 0x141, 0xF, 0xF, false); // row_half_mirror
    v.f = fmaxf(v.f, r.f);
    r.i = __builtin_amdgcn_update_dpp(v.i, v.i, 0x140, 0xF, 0xF, false); // row_mirror
    v.f = fmaxf(v.f, r.f);
    return v.f;
}

// XOR-swizzled LDS half-index (T2). Involution; writes and reads both use it.
__device__ __forceinline__ int swzi(int row, int colh, int ldh) {
    return row * ldh + (colh ^ ((row & 7) << 3));
}

// ---------------------------------------------------------------------------
// pack_x: build packed A = [x_r | x_i]  (M, 2048) fp16, row-major.
// Round 11: vectorized (float4 x2 read, u16x8 write) — was scalar 4B/lane.
// ---------------------------------------------------------------------------
struct PackXEnt { const float* r; const float* i; _Float16* dst; };
struct PackXBatch { PackXEnt e[2]; };

__global__ __launch_bounds__(256) void pack_x_kernel(PackXBatch b)
{
    PackXEnt e = b.e[blockIdx.z];
    const size_t total8 = (size_t)MM * GK / 8;     // 8-half spans
    for (size_t s = (size_t)blockIdx.x * 256 + threadIdx.x; s < total8;
         s += (size_t)gridDim.x * 256) {
        size_t m = s >> 8;                         // 256 spans per row
        int c8 = (int)(s & 255) * 8;               // half-col (multiple of 8)
        const float* src = (c8 < CH) ? (e.r + m * CH + c8)
                                     : (e.i + m * CH + (c8 - CH));
        float4 a = *(const float4*)(src);
        float4 c = *(const float4*)(src + 4);
        u16x8 o;
        o[0] = h2u((_Float16)a.x); o[1] = h2u((_Float16)a.y);
        o[2] = h2u((_Float16)a.z); o[3] = h2u((_Float16)a.w);
        o[4] = h2u((_Float16)c.x); o[5] = h2u((_Float16)c.y);
        o[6] = h2u((_Float16)c.z); o[7] = h2u((_Float16)c.w);
        *(u16x8*)(e.dst + s * 8) = o;
    }
}

// ---------------------------------------------------------------------------
// pack_w: Bt (N=1024, K=2048) fp16 = transposed packed weights. (unchanged)
// ---------------------------------------------------------------------------
struct PackWEnt { const float* a; const float* b; float signb; _Float16* dst; };
struct PackWBatch { PackWEnt e[8]; };

__global__ __launch_bounds__(256) void pack_w_kernel(PackWBatch bt)
{
    PackWEnt e = bt.e[blockIdx.z];
    const int k0 = blockIdx.x * 32;
    const int n0 = blockIdx.y * 32;
    const float* src = (k0 < CH) ? e.a : e.b;
    const float sign = (k0 < CH) ? 1.f : e.signb;
    const int kk = k0 & (CH - 1);

    __shared__ float sT[32][33];
    const int t = threadIdx.x;
    const int tx = t & 31, ty = t >> 5;

    #pragma unroll
    for (int r = 0; r < 4; r++) {
        int kl = ty + r * 8;
        sT[kl][tx] = src[(size_t)(kk + kl) * CH + n0 + tx] * sign;
    }
    __syncthreads();
    #pragma unroll
    for (int r = 0; r < 4; r++) {
        int nl = ty + r * 8;
        e.dst[(size_t)(n0 + nl) * GK + k0 + tx] = (_Float16)sT[tx][nl];
    }
}

// ---------------------------------------------------------------------------
// fp16 MFMA GEMM, round 11: A-operand DIRECT from global to registers
// (fragment layout == coalesced global layout; A has no cross-wave reuse),
// B via 4-slot gload_lds ring in LDS (4-way cross-wave reuse). Cuts LDS
// traffic 96->40 KB per K-step, LDS 96->32 KB, ONE barrier per K-step,
// counted vmcnt(5) steady state (A-prefetch + B-stage stay in flight).
// 256x128 tile, BK=32, 8 waves (4M x 2N, 64x64/wave), even-odd unrolled
// A register double-buffer (static indices, rule #20).
// Epilogue modes: 0 = head-packed QK fp16; 1 = head-packed V^T; 2 = fp32+bias.
// ---------------------------------------------------------------------------
struct GemmEnt { const _Float16* A; const _Float16* Bt; void* out;
                 const float* bias; int mode; int part; };
struct GemmBatch { GemmEnt e[6]; };

#define NT   (GK / 32)   // 64 K-steps
#define SWZ(x) ((x) ^ ((((x) >> 7) & 3) << 4))

__global__ __launch_bounds__(512, 2) void mfma_cgemm(GemmBatch bt)
{
    GemmEnt e = bt.e[blockIdx.z];
    __shared__ unsigned short lds[4 * 4096];   // 32 KiB: 4-slot B ring (128x32)

    const int t    = threadIdx.x;
    const int wave = t >> 6;
    const int lane = t & 63;
    const int lm   = lane & 15;
    const int quad = lane >> 4;
    const int wr   = wave >> 1;        // 0..3 -> 64-row M band
    const int wc   = wave & 1;         // 0..1 -> 64-col N band

    const int m0 = blockIdx.y * 256;
    const int n0 = blockIdx.x * 128;

    // B staging coords (pre-swizzled global source; LDS dest linear)
    const int pq   = SWZ(t * 16);
    const int sbrow = pq >> 6;             // 0..127
    const int sbcol = (pq >> 1) & 31;      // half col within BK=32

    const _Float16* gB = e.Bt + (size_t)n0 * GK;

    // A fragment row pointers (direct global; quad covers contiguous 64B/row)
    const _Float16* gAr[4];
    #pragma unroll
    for (int i = 0; i < 4; i++)
        gAr[i] = e.A + (size_t)(m0 + wr * 64 + i * 16 + lm) * GK + quad * 8;

    // swizzled B ds_read base (within slot)
    const int physB = SWZ((wc * 64 + lm) * 64 + quad * 16) >> 1;

    f32x4 acc[4][4] = {};
    f16x8 afA[4], afB[4];

    auto stageB = [&](int kt) {
        gload16(gB + (size_t)sbrow * GK + kt * 32 + sbcol,
                lds + (kt & 3) * 4096 + t * 8);
    };

    // prologue: A(0) to regs, B tiles 0..2 staged; wait A(0)+B(0) landed
    #pragma unroll
    for (int i = 0; i < 4; i++) afA[i] = *(const f16x8*)(gAr[i]);
    stageB(0); stageB(1); stageB(2);
    asm volatile("s_waitcnt vmcnt(2)" ::: "memory");
    __builtin_amdgcn_s_barrier();

    auto kstep = [&](int kt, f16x8 (&use)[4], f16x8 (&pre)[4]) {
        const unsigned short* buf = lds + (kt & 3) * 4096;
        f16x8 bf[4];
        #pragma unroll
        for (int j = 0; j < 4; j++)
            bf[j] = *(const f16x8*)&buf[physB + j * 512];
        if (kt + 1 < NT) {
            #pragma unroll
            for (int i = 0; i < 4; i++)
                pre[i] = *(const f16x8*)(gAr[i] + (kt + 1) * 32);
        }
        if (kt + 3 < NT) stageB(kt + 3);
        // counted drains: leave newest {A-prefetch, B-stage} in flight;
        // guarantee afc (issued last iter) + B(kt) (issued 3 iters ago) landed.
        if (kt < NT - 3)       asm volatile("s_waitcnt vmcnt(5)" ::: "memory");
        else if (kt <  NT - 1) asm volatile("s_waitcnt vmcnt(4)" ::: "memory");
        else                   asm volatile("s_waitcnt vmcnt(0)" ::: "memory");
        __builtin_amdgcn_s_setprio(1);
        #pragma unroll
        for (int i = 0; i < 4; i++)
            #pragma unroll
            for (int j = 0; j < 4; j++)
                acc[i][j] = __builtin_amdgcn_mfma_f32_16x16x32_f16(
                    use[i], bf[j], acc[i][j], 0, 0, 0);
        __builtin_amdgcn_s_setprio(0);
        __builtin_amdgcn_s_barrier();   // WAR: slot (kt+1)&3 restaged next iter
    };

    for (int kt = 0; kt < NT; kt += 2) {
        kstep(kt,     afA, afB);
        kstep(kt + 1, afB, afA);
    }

    const int mode = e.mode, part = e.part;
    #pragma unroll
    for (int j = 0; j < 4; j++) {
        int gcol = n0 + wc * 64 + j * 16 + lm;
        float bv = (mode == 2 && e.bias) ? e.bias[gcol] : 0.f;
        #pragma unroll
        for (int i = 0; i < 4; i++) {
            int growb = m0 + wr * 64 + i * 16 + quad * 4;
            #pragma unroll
            for (int reg = 0; reg < 4; reg++) {
                int grow = growb + reg;
                float v = acc[i][j][reg];
                if (mode == 2) {
                    ((float*)e.out)[(size_t)grow * CH + gcol] = v + bv;
                } else {
                    int b = grow >> 11, l = grow & 2047;
                    int h = gcol >> 6, dd = gcol & 63;
                    size_t off;
                    if (mode == 0)
                        off = (((size_t)(b * NH + h)) * LQ + l) * 128 + part * 64 + dd;
                    else
                        off = (((size_t)(b * NH + h)) * 128 + part * 64 + dd) * SK + l;
                    ((_Float16*)e.out)[off] = (_Float16)v;
                }
            }
        }
    }
}

// ---------------------------------------------------------------------------
// MFMA flash attention (round-10 structure, unchanged — verified improvement):
// 256-row Q-tile, 512 thr / 8 waves / 1 block per CU; Q direct to regs;
// XCD-bijective swizzle (4 K/V streams per XCD); T2 LDS swizzle; T13
// wave-uniform defer-max.
// LDS (halfs): sP 256x64 @0, sK 64x128 @16384, sV 144x64 @24576 (67584 B).
// ---------------------------------------------------------------------------
__global__ __launch_bounds__(512, 2) void attn_mfma(
    const _Float16* __restrict__ Qp, const _Float16* __restrict__ Kp,
    const _Float16* __restrict__ Vt, _Float16* __restrict__ Aattn)
{
    __shared__ unsigned short lds[33792];
    unsigned short* sP = lds;            // 256 x 64 (swz, ld 64)
    unsigned short* sK = lds + 16384;    // 64 x 128 (swz, ld 128)
    unsigned short* sV = lds + 24576;    // 144 x 64 (swz, ld 64)

    const int t    = threadIdx.x;
    const int w    = t >> 6;             // 0..7
    const int lane = t & 63;
    const int lm   = lane & 15;
    const int quad = lane >> 4;

    const int bx  = blockIdx.x;
    const int bid = (bx & 7) * 32 + (bx >> 3);
    const int mt  = bid & 7;             // Q tile (256 rows), 0..7
    const int h   = (bid >> 3) & 15;
    const int b   = bid >> 7;

    const _Float16* qb = Qp + (((size_t)(b * NH + h)) * LQ + (size_t)mt * 256) * 128;
    const _Float16* kb = Kp + ((size_t)(b * NH + h)) * SK * 128;
    const _Float16* vb = Vt + ((size_t)(b * NH + h)) * 128 * SK;

    // ones tail rows of sV (rows 128..143): the l-accumulator trick
    for (int idx = t; idx < 16 * 64; idx += 512) {
        int row = 128 + (idx >> 6);
        int col = idx & 63;
        sV[row * 64 + (col ^ ((row & 7) << 3))] = 0x3C00;   // fp16 1.0
    }

    // Q -> A-frags DIRECTLY from global (held for whole kernel)
    f16x8 qf[2][4];
    #pragma unroll
    for (int i = 0; i < 2; i++)
        #pragma unroll
        for (int kk = 0; kk < 4; kk++)
            qf[i][kk] = *(const f16x8*)(qb + (size_t)(w * 32 + i * 16 + lm) * 128
                                           + kk * 32 + quad * 8);

    // preload K/V tile 0 into regs
    u16x8 kreg[2], vreg[2];
    #pragma unroll
    for (int p = 0; p < 2; p++) {
        int idx = p * 512 + t;
        int r = idx >> 4, sg = idx & 15;
        kreg[p] = *(const u16x8*)(kb + (size_t)r * 128 + sg * 8);
        int rv = idx >> 3, sv = idx & 7;
        vreg[p] = *(const u16x8*)(vb + (size_t)rv * SK + sv * 8);
    }

    f32x4 oacc[2][9] = {};
    float m_st[2][4];
    #pragma unroll
    for (int i = 0; i < 2; i++)
        #pragma unroll
        for (int r = 0; r < 4; r++) m_st[i][r] = -1e30f;

    const float SC2 = ATT_SCALE * 1.44269504f;   // exp2 domain

    for (int it = 0; it < SK / 64; ++it) {
        __syncthreads();                         // WAR: prev PV reads vs staging
        #pragma unroll
        for (int p = 0; p < 2; p++) {
            int idx = p * 512 + t;
            int r = idx >> 4, sg = idx & 15;
            *(u16x8*)&sK[swzi(r, sg * 8, 128)] = kreg[p];
            int rv = idx >> 3, sv = idx & 7;
            *(u16x8*)&sV[swzi(rv, sv * 8, 64)] = vreg[p];
        }
        __syncthreads();

        if (it + 1 < SK / 64) {                  // prefetch next tile
            int s0n = (it + 1) * 64;
            #pragma unroll
            for (int p = 0; p < 2; p++) {
                int idx = p * 512 + t;
                int r = idx >> 4, sg = idx & 15;
                kreg[p] = *(const u16x8*)(kb + (size_t)(s0n + r) * 128 + sg * 8);
                int rv = idx >> 3, sv = idx & 7;
                vreg[p] = *(const u16x8*)(vb + (size_t)rv * SK + s0n + sv * 8);
            }
        }

        // ---- QK^T: wave rows 32 x cols 64, k = 128 (Q from regs) ----
        f32x4 sacc[2][4] = {};
        #pragma unroll
        for (int kk = 0; kk < 4; kk++) {
            f16x8 bfr[4];
            #pragma unroll
            for (int j = 0; j < 4; j++)
                bfr[j] = *(const f16x8*)&sK[swzi(j * 16 + lm, kk * 32 + quad * 8, 128)];
            #pragma unroll
            for (int i = 0; i < 2; i++)
                #pragma unroll
                for (int j = 0; j < 4; j++)
                    sacc[i][j] = __builtin_amdgcn_mfma_f32_16x16x32_f16(
                        qf[i][kk], bfr[j], sacc[i][j], 0, 0, 0);
        }

        // ---- online softmax (T13, wave-uniform rare-rescale) ----
        float mx[2][4];
        #pragma unroll
        for (int i = 0; i < 2; i++)
            #pragma unroll
            for (int r = 0; r < 4; r++) {
                float m4 = fmaxf(fmaxf(sacc[i][0][r], sacc[i][1][r]),
                                 fmaxf(sacc[i][2][r], sacc[i][3][r]));
                mx[i][r] = dpp_max16(m4) * SC2;
            }
        int need = 0;
        #pragma unroll
        for (int i = 0; i < 2; i++)
            #pragma unroll
            for (int r = 0; r < 4; r++)
                need |= (mx[i][r] > m_st[i][r] + 8.0f) ? 1 : 0;
        if (__any(need)) {
            #pragma unroll
            for (int i = 0; i < 2; i++)
                #pragma unroll
                for (int r = 0; r < 4; r++) {
                    float mnew = fmaxf(m_st[i][r], mx[i][r]);
                    float al = exp2f(m_st[i][r] - mnew);
                    m_st[i][r] = mnew;
                    #pragma unroll
                    for (int j2 = 0; j2 < 9; j2++)
                        oacc[i][j2][r] *= al;
                }
        }
        #pragma unroll
        for (int i = 0; i < 2; i++)
            #pragma unroll
            for (int r = 0; r < 4; r++) {
                float mcur = m_st[i][r];
                int rowp = w * 32 + i * 16 + quad * 4 + r;
                #pragma unroll
                for (int j = 0; j < 4; j++) {
                    float p = exp2f(sacc[i][j][r] * SC2 - mcur);
                    sP[swzi(rowp, j * 16 + lm, 64)] = h2u((_Float16)p);
                }
            }

        // ---- PV: O[m][d] += P[m][s] * Vt[d][s]; j2=8 (ones rows) -> l ----
        #pragma unroll
        for (int kk = 0; kk < 2; kk++) {
            f16x8 pf[2], vf[9];
            #pragma unroll
            for (int i = 0; i < 2; i++)
                pf[i] = *(const f16x8*)&sP[swzi(w * 32 + i * 16 + lm, kk * 32 + quad * 8, 64)];
            #pragma unroll
            for (int j2 = 0; j2 < 9; j2++)
                vf[j2] = *(const f16x8*)&sV[swzi(j2 * 16 + lm, kk * 32 + quad * 8, 64)];
            #pragma unroll
            for (int i = 0; i < 2; i++)
                #pragma unroll
                for (int j2 = 0; j2 < 9; j2++)
                    oacc[i][j2] = __builtin_amdgcn_mfma_f32_16x16x32_f16(
                        pf[i], vf[j2], oacc[i][j2], 0, 0, 0);
        }
    }

    // ---- epilogue: l = oacc[i][8][r] (valid in every lane); normalize ----
    #pragma unroll
    for (int i = 0; i < 2; i++) {
        #pragma unroll
        for (int r = 0; r < 4; r++) {
            float inv = 1.f / oacc[i][8][r];
            int ml = w * 32 + i * 16 + quad * 4 + r;
            size_t row = (size_t)b * LQ + (size_t)mt * 256 + ml;
            #pragma unroll
            for (int j2 = 0; j2 < 8; j2++) {
                int d = j2 * 16 + lm;
                int dcol = (d < HD) ? h * HD + d : CH + h * HD + (d - HD);
                Aattn[row * GK + dcol] = (_Float16)(oacc[i][j2][r] * inv);
            }
        }
    }
}

// ---------------------------------------------------------------------------
extern "C" void kernel_launch(void* const* d_in, const int* in_sizes, int n_in,
                              void* d_out, int out_size, void* d_ws, size_t ws_size,
                              hipStream_t stream)
{
    const float* in_r = (const float*)d_in[0];
    const float* in_i = (const float*)d_in[1];
    const float* cx_r = (const float*)d_in[2];
    const float* cx_i = (const float*)d_in[3];
    const float* wq_r = (const float*)d_in[4];
    const float* wq_i = (const float*)d_in[5];
    const float* wk_r = (const float*)d_in[6];
    const float* wk_i = (const float*)d_in[7];
    const float* wv_r = (const float*)d_in[8];
    const float* wv_i = (const float*)d_in[9];
    const float* wo_r = (const float*)d_in[10];
    const float* wo_i = (const float*)d_in[11];
    const float* bo_r = (const float*)d_in[12];
    const float* bo_i = (const float*)d_in[13];

    _Float16* ws = (_Float16*)d_ws;
    const size_t A_ELEMS = (size_t)MM * GK;
    const size_t B_ELEMS = (size_t)CH * GK;
    const size_t H_ELEMS = (size_t)BB * NH * LQ * 128;

    _Float16* Ain   = ws;
    _Float16* Aattn = ws;                          // alias (Ain dead after qkv GEMM)
    _Float16* Actx  = Ain + A_ELEMS;
    _Float16* Bp    = Actx + A_ELEMS;
    _Float16* Qp    = Bp + 8 * B_ELEMS;
    _Float16* Kp    = Qp + H_ELEMS;
    _Float16* Vt    = Kp + H_ELEMS;

    _Float16* Bq_r = Bp + 0 * B_ELEMS;
    _Float16* Bq_i = Bp + 1 * B_ELEMS;
    _Float16* Bk_r = Bp + 2 * B_ELEMS;
    _Float16* Bk_i = Bp + 3 * B_ELEMS;
    _Float16* Bv_r = Bp + 4 * B_ELEMS;
    _Float16* Bv_i = Bp + 5 * B_ELEMS;
    _Float16* Bo_r = Bp + 6 * B_ELEMS;
    _Float16* Bo_i = Bp + 7 * B_ELEMS;

    float* out = (float*)d_out;
    float* yr = out;
    float* yi = out + (size_t)MM * CH;

    PackXBatch px;
    px.e[0] = { in_r, in_i, Ain  };
    px.e[1] = { cx_r, cx_i, Actx };
    pack_x_kernel<<<dim3(4096, 1, 2), 256, 0, stream>>>(px);

    PackWBatch pw;
    pw.e[0] = { wq_r, wq_i, -1.f, Bq_r };
    pw.e[1] = { wq_i, wq_r,  1.f, Bq_i };
    pw.e[2] = { wk_r, wk_i, -1.f, Bk_r };
    pw.e[3] = { wk_i, wk_r,  1.f, Bk_i };
    pw.e[4] = { wv_r, wv_i, -1.f, Bv_r };
    pw.e[5] = { wv_i, wv_r,  1.f, Bv_i };
    pw.e[6] = { wo_r, wo_i, -1.f, Bo_r };
    pw.e[7] = { wo_i, wo_r,  1.f, Bo_i };
    pack_w_kernel<<<dim3(GK / 32, CH / 32, 8), 256, 0, stream>>>(pw);

    GemmBatch gq;
    gq.e[0] = { Ain,  Bq_r, Qp, nullptr, 0, 0 };
    gq.e[1] = { Ain,  Bq_i, Qp, nullptr, 0, 1 };
    gq.e[2] = { Actx, Bk_r, Kp, nullptr, 0, 0 };
    gq.e[3] = { Actx, Bk_i, Kp, nullptr, 0, 1 };
    gq.e[4] = { Actx, Bv_r, Vt, nullptr, 1, 0 };
    gq.e[5] = { Actx, Bv_i, Vt, nullptr, 1, 1 };
    mfma_cgemm<<<dim3(CH / 128, MM / 256, 6), 512, 0, stream>>>(gq);

    attn_mfma<<<dim3(BB * NH * (LQ / 256)), 512, 0, stream>>>(Qp, Kp, Vt, Aattn);

    GemmBatch go;
    go.e[0] = { Aattn, Bo_r, yr, bo_r, 2, 0 };
    go.e[1] = { Aattn, Bo_i, yi, bo_i, 2, 1 };
    for (int z = 2; z < 6; z++) go.e[z] = go.e[0];
    mfma_cgemm<<<dim3(CH / 128, MM / 256, 2), 512, 0, stream>>>(go);
}

// Round 8
// 472.467 us; speedup vs baseline: 1.2911x; 1.2911x over previous
//
#include <hip/hip_runtime.h>

// Problem constants (fixed by reference setup_inputs)
#define BB 2
#define LQ 2048
#define SK 2048
#define CH 1024
#define NH 16
#define HD 64
#define GK 2048          // packed complex K (= 2*CH)
#define MM 4096          // B*L = B*S
#define ATT_SCALE 0.125f // 1/sqrt(64)

typedef _Float16 f16x8 __attribute__((ext_vector_type(8)));
typedef float f32x4 __attribute__((ext_vector_type(4)));
typedef unsigned short u16x8 __attribute__((ext_vector_type(8)));

__device__ __forceinline__ unsigned short h2u(_Float16 h) {
    union { _Float16 h; unsigned short u; } v; v.h = h; return v.u;
}
__device__ __forceinline__ void gload16(const _Float16* g, unsigned short* l) {
    __builtin_amdgcn_global_load_lds(
        (const __attribute__((address_space(1))) void*)g,
        (__attribute__((address_space(3))) void*)l, 16, 0, 0);
}

// 16-lane all-reduce max via DPP (full-rate VALU, no LDS pipe).
__device__ __forceinline__ float dpp_max16(float x) {
    union { float f; int i; } v, r;
    v.f = x;
    r.i = __builtin_amdgcn_update_dpp(v.i, v.i, 0xB1, 0xF, 0xF, false);  // quad_perm [1,0,3,2]
    v.f = fmaxf(v.f, r.f);
    r.i = __builtin_amdgcn_update_dpp(v.i, v.i, 0x4E, 0xF, 0xF, false);  // quad_perm [2,3,0,1]
    v.f = fmaxf(v.f, r.f);
    r.i = __builtin_amdgcn_update_dpp(v.i, v.i, 0x141, 0xF, 0xF, false); // row_half_mirror
    v.f = fmaxf(v.f, r.f);
    r.i = __builtin_amdgcn_update_dpp(v.i, v.i, 0x140, 0xF, 0xF, false); // row_mirror
    v.f = fmaxf(v.f, r.f);
    return v.f;
}

// XOR-swizzled LDS half-index (T2). Involution; writes and reads both use it.
__device__ __forceinline__ int swzi(int row, int colh, int ldh) {
    return row * ldh + (colh ^ ((row & 7) << 3));
}

// ---------------------------------------------------------------------------
// pack_x: build packed A = [x_r | x_i]  (M, 2048) fp16, row-major.
// Vectorized (float4 x2 read, u16x8 write).
// ---------------------------------------------------------------------------
struct PackXEnt { const float* r; const float* i; _Float16* dst; };
struct PackXBatch { PackXEnt e[2]; };

__global__ __launch_bounds__(256) void pack_x_kernel(PackXBatch b)
{
    PackXEnt e = b.e[blockIdx.z];
    const size_t total8 = (size_t)MM * GK / 8;     // 8-half spans
    for (size_t s = (size_t)blockIdx.x * 256 + threadIdx.x; s < total8;
         s += (size_t)gridDim.x * 256) {
        size_t m = s >> 8;                         // 256 spans per row
        int c8 = (int)(s & 255) * 8;               // half-col (multiple of 8)
        const float* src = (c8 < CH) ? (e.r + m * CH + c8)
                                     : (e.i + m * CH + (c8 - CH));
        float4 a = *(const float4*)(src);
        float4 c = *(const float4*)(src + 4);
        u16x8 o;
        o[0] = h2u((_Float16)a.x); o[1] = h2u((_Float16)a.y);
        o[2] = h2u((_Float16)a.z); o[3] = h2u((_Float16)a.w);
        o[4] = h2u((_Float16)c.x); o[5] = h2u((_Float16)c.y);
        o[6] = h2u((_Float16)c.z); o[7] = h2u((_Float16)c.w);
        *(u16x8*)(e.dst + s * 8) = o;
    }
}

// ---------------------------------------------------------------------------
// pack_w: Bt (N=1024, K=2048) fp16 = transposed packed weights. (unchanged)
// ---------------------------------------------------------------------------
struct PackWEnt { const float* a; const float* b; float signb; _Float16* dst; };
struct PackWBatch { PackWEnt e[8]; };

__global__ __launch_bounds__(256) void pack_w_kernel(PackWBatch bt)
{
    PackWEnt e = bt.e[blockIdx.z];
    const int k0 = blockIdx.x * 32;
    const int n0 = blockIdx.y * 32;
    const float* src = (k0 < CH) ? e.a : e.b;
    const float sign = (k0 < CH) ? 1.f : e.signb;
    const int kk = k0 & (CH - 1);

    __shared__ float sT[32][33];
    const int t = threadIdx.x;
    const int tx = t & 31, ty = t >> 5;

    #pragma unroll
    for (int r = 0; r < 4; r++) {
        int kl = ty + r * 8;
        sT[kl][tx] = src[(size_t)(kk + kl) * CH + n0 + tx] * sign;
    }
    __syncthreads();
    #pragma unroll
    for (int r = 0; r < 4; r++) {
        int nl = ty + r * 8;
        e.dst[(size_t)(n0 + nl) * GK + k0 + tx] = (_Float16)sT[tx][nl];
    }
}

// ---------------------------------------------------------------------------
// fp16 MFMA GEMM, round 12: REVERT to round-6 A+B gload_lds ring (A-direct
// regressed: 16-row scattered 64B gathers choke the request path), with ONE
// structural change: single barrier per K-step, ds_reads AFTER the barrier,
// no explicit lgkmcnt(0) — compiler-counted lgkmcnt interleaves each wave's
// ds_reads with its MFMAs, overlapping the LDS phase with the MFMA phase
// across waves. vmcnt(6)-before-barrier handoff unchanged (per-wave staged
// data landed -> barrier -> other waves read).
// 256x128 tile, BK=32, 8 waves (4M x 2N, 64x64/wave), 4-slot ring (96 KiB).
// Epilogue modes: 0 = head-packed QK fp16; 1 = head-packed V^T; 2 = fp32+bias.
// ---------------------------------------------------------------------------
struct GemmEnt { const _Float16* A; const _Float16* Bt; void* out;
                 const float* bias; int mode; int part; };
struct GemmBatch { GemmEnt e[6]; };

#define NT   (GK / 32)   // 64 K-steps
#define BUFH 12288       // halfs per ring slot: A 256x32 (8192) + B 128x32 (4096)

#define SWZ(x) ((x) ^ ((((x) >> 7) & 3) << 4))

__global__ __launch_bounds__(512, 2) void mfma_cgemm(GemmBatch bt)
{
    GemmEnt e = bt.e[blockIdx.z];
    __shared__ unsigned short lds[4 * BUFH];   // 96 KiB, 4-slot ring

    const int t    = threadIdx.x;
    const int wave = t >> 6;
    const int lane = t & 63;
    const int lm   = lane & 15;
    const int quad = lane >> 4;
    const int wr   = wave >> 1;        // 0..3 -> 64-row M band
    const int wc   = wave & 1;         // 0..1 -> 64-col N band

    const int m0 = blockIdx.y * 256;
    const int n0 = blockIdx.x * 128;

    int srow[2], scol[2];
    #pragma unroll
    for (int L = 0; L < 2; L++) {
        int p = (L * 512 + t) * 16;
        int q = SWZ(p);
        srow[L] = q >> 6;
        scol[L] = (q >> 1) & 31;
    }

    const _Float16* gA = e.A  + (size_t)m0 * GK;
    const _Float16* gB = e.Bt + (size_t)n0 * GK;

    auto stage = [&](int kt) {
        unsigned short* base = lds + (kt & 3) * BUFH;
        #pragma unroll
        for (int L = 0; L < 2; L++)
            gload16(gA + (size_t)srow[L] * GK + kt * 32 + scol[L],
                    base + (L * 512 + t) * 8);
        gload16(gB + (size_t)srow[0] * GK + kt * 32 + scol[0],
                base + 8192 + t * 8);
    };

    const int qA    = (wr * 64 + lm) * 64 + quad * 16;
    const int physA = SWZ(qA) >> 1;
    const int qB    = (wc * 64 + lm) * 64 + quad * 16;
    const int physB = (SWZ(qB) >> 1) + 8192;

    f32x4 acc[4][4] = {};

    // prologue: stage tiles 0..2; ensure tile 0 landed (leave 6 in flight)
    stage(0); stage(1); stage(2);
    asm volatile("s_waitcnt vmcnt(6)" ::: "memory");

    for (int kt = 0; kt < NT; ++kt) {
        __builtin_amdgcn_s_barrier();   // staged slot kt&3 visible to all waves

        const unsigned short* buf = lds + (kt & 3) * BUFH;
        f16x8 af[4], bf[4];
        #pragma unroll
        for (int i = 0; i < 4; i++)
            af[i] = *(const f16x8*)&buf[physA + i * 512];
        #pragma unroll
        for (int j = 0; j < 4; j++)
            bf[j] = *(const f16x8*)&buf[physB + j * 512];

        if (kt + 3 < NT) stage(kt + 3);   // slot (kt+3)&3: consumed @ kt-1

        __builtin_amdgcn_s_setprio(1);
        #pragma unroll
        for (int i = 0; i < 4; i++)
            #pragma unroll
            for (int j = 0; j < 4; j++)
                acc[i][j] = __builtin_amdgcn_mfma_f32_16x16x32_f16(
                    af[i], bf[j], acc[i][j], 0, 0, 0);
        __builtin_amdgcn_s_setprio(0);

        // counted drain BEFORE next barrier: tile kt+1 (staged 2 iters ago)
        // must be landed; newest 2 stages (6 loads) stay in flight.
        if (kt < NT - 3)       asm volatile("s_waitcnt vmcnt(6)" ::: "memory");
        else if (kt == NT - 3) asm volatile("s_waitcnt vmcnt(3)" ::: "memory");
        else if (kt == NT - 2) asm volatile("s_waitcnt vmcnt(0)" ::: "memory");
    }

    const int mode = e.mode, part = e.part;
    #pragma unroll
    for (int j = 0; j < 4; j++) {
        int gcol = n0 + wc * 64 + j * 16 + lm;
        float bv = (mode == 2 && e.bias) ? e.bias[gcol] : 0.f;
        #pragma unroll
        for (int i = 0; i < 4; i++) {
            int growb = m0 + wr * 64 + i * 16 + quad * 4;
            #pragma unroll
            for (int reg = 0; reg < 4; reg++) {
                int grow = growb + reg;
                float v = acc[i][j][reg];
                if (mode == 2) {
                    ((float*)e.out)[(size_t)grow * CH + gcol] = v + bv;
                } else {
                    int b = grow >> 11, l = grow & 2047;
                    int h = gcol >> 6, dd = gcol & 63;
                    size_t off;
                    if (mode == 0)
                        off = (((size_t)(b * NH + h)) * LQ + l) * 128 + part * 64 + dd;
                    else
                        off = (((size_t)(b * NH + h)) * 128 + part * 64 + dd) * SK + l;
                    ((_Float16*)e.out)[off] = (_Float16)v;
                }
            }
        }
    }
}

// ---------------------------------------------------------------------------
// MFMA flash attention (round-10 structure, unchanged — verified improvement):
// 256-row Q-tile, 512 thr / 8 waves / 1 block per CU; Q direct to regs;
// XCD-bijective swizzle (4 K/V streams per XCD); T2 LDS swizzle; T13
// wave-uniform defer-max.
// LDS (halfs): sP 256x64 @0, sK 64x128 @16384, sV 144x64 @24576 (67584 B).
// ---------------------------------------------------------------------------
__global__ __launch_bounds__(512, 2) void attn_mfma(
    const _Float16* __restrict__ Qp, const _Float16* __restrict__ Kp,
    const _Float16* __restrict__ Vt, _Float16* __restrict__ Aattn)
{
    __shared__ unsigned short lds[33792];
    unsigned short* sP = lds;            // 256 x 64 (swz, ld 64)
    unsigned short* sK = lds + 16384;    // 64 x 128 (swz, ld 128)
    unsigned short* sV = lds + 24576;    // 144 x 64 (swz, ld 64)

    const int t    = threadIdx.x;
    const int w    = t >> 6;             // 0..7
    const int lane = t & 63;
    const int lm   = lane & 15;
    const int quad = lane >> 4;

    const int bx  = blockIdx.x;
    const int bid = (bx & 7) * 32 + (bx >> 3);
    const int mt  = bid & 7;             // Q tile (256 rows), 0..7
    const int h   = (bid >> 3) & 15;
    const int b   = bid >> 7;

    const _Float16* qb = Qp + (((size_t)(b * NH + h)) * LQ + (size_t)mt * 256) * 128;
    const _Float16* kb = Kp + ((size_t)(b * NH + h)) * SK * 128;
    const _Float16* vb = Vt + ((size_t)(b * NH + h)) * 128 * SK;

    // ones tail rows of sV (rows 128..143): the l-accumulator trick
    for (int idx = t; idx < 16 * 64; idx += 512) {
        int row = 128 + (idx >> 6);
        int col = idx & 63;
        sV[row * 64 + (col ^ ((row & 7) << 3))] = 0x3C00;   // fp16 1.0
    }

    // Q -> A-frags DIRECTLY from global (held for whole kernel)
    f16x8 qf[2][4];
    #pragma unroll
    for (int i = 0; i < 2; i++)
        #pragma unroll
        for (int kk = 0; kk < 4; kk++)
            qf[i][kk] = *(const f16x8*)(qb + (size_t)(w * 32 + i * 16 + lm) * 128
                                           + kk * 32 + quad * 8);

    // preload K/V tile 0 into regs
    u16x8 kreg[2], vreg[2];
    #pragma unroll
    for (int p = 0; p < 2; p++) {
        int idx = p * 512 + t;
        int r = idx >> 4, sg = idx & 15;
        kreg[p] = *(const u16x8*)(kb + (size_t)r * 128 + sg * 8);
        int rv = idx >> 3, sv = idx & 7;
        vreg[p] = *(const u16x8*)(vb + (size_t)rv * SK + sv * 8);
    }

    f32x4 oacc[2][9] = {};
    float m_st[2][4];
    #pragma unroll
    for (int i = 0; i < 2; i++)
        #pragma unroll
        for (int r = 0; r < 4; r++) m_st[i][r] = -1e30f;

    const float SC2 = ATT_SCALE * 1.44269504f;   // exp2 domain

    for (int it = 0; it < SK / 64; ++it) {
        __syncthreads();                         // WAR: prev PV reads vs staging
        #pragma unroll
        for (int p = 0; p < 2; p++) {
            int idx = p * 512 + t;
            int r = idx >> 4, sg = idx & 15;
            *(u16x8*)&sK[swzi(r, sg * 8, 128)] = kreg[p];
            int rv = idx >> 3, sv = idx & 7;
            *(u16x8*)&sV[swzi(rv, sv * 8, 64)] = vreg[p];
        }
        __syncthreads();

        if (it + 1 < SK / 64) {                  // prefetch next tile
            int s0n = (it + 1) * 64;
            #pragma unroll
            for (int p = 0; p < 2; p++) {
                int idx = p * 512 + t;
                int r = idx >> 4, sg = idx & 15;
                kreg[p] = *(const u16x8*)(kb + (size_t)(s0n + r) * 128 + sg * 8);
                int rv = idx >> 3, sv = idx & 7;
                vreg[p] = *(const u16x8*)(vb + (size_t)rv * SK + s0n + sv * 8);
            }
        }

        // ---- QK^T: wave rows 32 x cols 64, k = 128 (Q from regs) ----
        f32x4 sacc[2][4] = {};
        #pragma unroll
        for (int kk = 0; kk < 4; kk++) {
            f16x8 bfr[4];
            #pragma unroll
            for (int j = 0; j < 4; j++)
                bfr[j] = *(const f16x8*)&sK[swzi(j * 16 + lm, kk * 32 + quad * 8, 128)];
            #pragma unroll
            for (int i = 0; i < 2; i++)
                #pragma unroll
                for (int j = 0; j < 4; j++)
                    sacc[i][j] = __builtin_amdgcn_mfma_f32_16x16x32_f16(
                        qf[i][kk], bfr[j], sacc[i][j], 0, 0, 0);
        }

        // ---- online softmax (T13, wave-uniform rare-rescale) ----
        float mx[2][4];
        #pragma unroll
        for (int i = 0; i < 2; i++)
            #pragma unroll
            for (int r = 0; r < 4; r++) {
                float m4 = fmaxf(fmaxf(sacc[i][0][r], sacc[i][1][r]),
                                 fmaxf(sacc[i][2][r], sacc[i][3][r]));
                mx[i][r] = dpp_max16(m4) * SC2;
            }
        int need = 0;
        #pragma unroll
        for (int i = 0; i < 2; i++)
            #pragma unroll
            for (int r = 0; r < 4; r++)
                need |= (mx[i][r] > m_st[i][r] + 8.0f) ? 1 : 0;
        if (__any(need)) {
            #pragma unroll
            for (int i = 0; i < 2; i++)
                #pragma unroll
                for (int r = 0; r < 4; r++) {
                    float mnew = fmaxf(m_st[i][r], mx[i][r]);
                    float al = exp2f(m_st[i][r] - mnew);
                    m_st[i][r] = mnew;
                    #pragma unroll
                    for (int j2 = 0; j2 < 9; j2++)
                        oacc[i][j2][r] *= al;
                }
        }
        #pragma unroll
        for (int i = 0; i < 2; i++)
            #pragma unroll
            for (int r = 0; r < 4; r++) {
                float mcur = m_st[i][r];
                int rowp = w * 32 + i * 16 + quad * 4 + r;
                #pragma unroll
                for (int j = 0; j < 4; j++) {
                    float p = exp2f(sacc[i][j][r] * SC2 - mcur);
                    sP[swzi(rowp, j * 16 + lm, 64)] = h2u((_Float16)p);
                }
            }

        // ---- PV: O[m][d] += P[m][s] * Vt[d][s]; j2=8 (ones rows) -> l ----
        #pragma unroll
        for (int kk = 0; kk < 2; kk++) {
            f16x8 pf[2], vf[9];
            #pragma unroll
            for (int i = 0; i < 2; i++)
                pf[i] = *(const f16x8*)&sP[swzi(w * 32 + i * 16 + lm, kk * 32 + quad * 8, 64)];
            #pragma unroll
            for (int j2 = 0; j2 < 9; j2++)
                vf[j2] = *(const f16x8*)&sV[swzi(j2 * 16 + lm, kk * 32 + quad * 8, 64)];
            #pragma unroll
            for (int i = 0; i < 2; i++)
                #pragma unroll
                for (int j2 = 0; j2 < 9; j2++)
                    oacc[i][j2] = __builtin_amdgcn_mfma_f32_16x16x32_f16(
                        pf[i], vf[j2], oacc[i][j2], 0, 0, 0);
        }
    }

    // ---- epilogue: l = oacc[i][8][r] (valid in every lane); normalize ----
    #pragma unroll
    for (int i = 0; i < 2; i++) {
        #pragma unroll
        for (int r = 0; r < 4; r++) {
            float inv = 1.f / oacc[i][8][r];
            int ml = w * 32 + i * 16 + quad * 4 + r;
            size_t row = (size_t)b * LQ + (size_t)mt * 256 + ml;
            #pragma unroll
            for (int j2 = 0; j2 < 8; j2++) {
                int d = j2 * 16 + lm;
                int dcol = (d < HD) ? h * HD + d : CH + h * HD + (d - HD);
                Aattn[row * GK + dcol] = (_Float16)(oacc[i][j2][r] * inv);
            }
        }
    }
}

// ---------------------------------------------------------------------------
extern "C" void kernel_launch(void* const* d_in, const int* in_sizes, int n_in,
                              void* d_out, int out_size, void* d_ws, size_t ws_size,
                              hipStream_t stream)
{
    const float* in_r = (const float*)d_in[0];
    const float* in_i = (const float*)d_in[1];
    const float* cx_r = (const float*)d_in[2];
    const float* cx_i = (const float*)d_in[3];
    const float* wq_r = (const float*)d_in[4];
    const float* wq_i = (const float*)d_in[5];
    const float* wk_r = (const float*)d_in[6];
    const float* wk_i = (const float*)d_in[7];
    const float* wv_r = (const float*)d_in[8];
    const float* wv_i = (const float*)d_in[9];
    const float* wo_r = (const float*)d_in[10];
    const float* wo_i = (const float*)d_in[11];
    const float* bo_r = (const float*)d_in[12];
    const float* bo_i = (const float*)d_in[13];

    _Float16* ws = (_Float16*)d_ws;
    const size_t A_ELEMS = (size_t)MM * GK;
    const size_t B_ELEMS = (size_t)CH * GK;
    const size_t H_ELEMS = (size_t)BB * NH * LQ * 128;

    _Float16* Ain   = ws;
    _Float16* Aattn = ws;                          // alias (Ain dead after qkv GEMM)
    _Float16* Actx  = Ain + A_ELEMS;
    _Float16* Bp    = Actx + A_ELEMS;
    _Float16* Qp    = Bp + 8 * B_ELEMS;
    _Float16* Kp    = Qp + H_ELEMS;
    _Float16* Vt    = Kp + H_ELEMS;

    _Float16* Bq_r = Bp + 0 * B_ELEMS;
    _Float16* Bq_i = Bp + 1 * B_ELEMS;
    _Float16* Bk_r = Bp + 2 * B_ELEMS;
    _Float16* Bk_i = Bp + 3 * B_ELEMS;
    _Float16* Bv_r = Bp + 4 * B_ELEMS;
    _Float16* Bv_i = Bp + 5 * B_ELEMS;
    _Float16* Bo_r = Bp + 6 * B_ELEMS;
    _Float16* Bo_i = Bp + 7 * B_ELEMS;

    float* out = (float*)d_out;
    float* yr = out;
    float* yi = out + (size_t)MM * CH;

    PackXBatch px;
    px.e[0] = { in_r, in_i, Ain  };
    px.e[1] = { cx_r, cx_i, Actx };
    pack_x_kernel<<<dim3(2048, 1, 2), 256, 0, stream>>>(px);

    PackWBatch pw;
    pw.e[0] = { wq_r, wq_i, -1.f, Bq_r };
    pw.e[1] = { wq_i, wq_r,  1.f, Bq_i };
    pw.e[2] = { wk_r, wk_i, -1.f, Bk_r };
    pw.e[3] = { wk_i, wk_r,  1.f, Bk_i };
    pw.e[4] = { wv_r, wv_i, -1.f, Bv_r };
    pw.e[5] = { wv_i, wv_r,  1.f, Bv_i };
    pw.e[6] = { wo_r, wo_i, -1.f, Bo_r };
    pw.e[7] = { wo_i, wo_r,  1.f, Bo_i };
    pack_w_kernel<<<dim3(GK / 32, CH / 32, 8), 256, 0, stream>>>(pw);

    GemmBatch gq;
    gq.e[0] = { Ain,  Bq_r, Qp, nullptr, 0, 0 };
    gq.e[1] = { Ain,  Bq_i, Qp, nullptr, 0, 1 };
    gq.e[2] = { Actx, Bk_r, Kp, nullptr, 0, 0 };
    gq.e[3] = { Actx, Bk_i, Kp, nullptr, 0, 1 };
    gq.e[4] = { Actx, Bv_r, Vt, nullptr, 1, 0 };
    gq.e[5] = { Actx, Bv_i, Vt, nullptr, 1, 1 };
    mfma_cgemm<<<dim3(CH / 128, MM / 256, 6), 512, 0, stream>>>(gq);

    attn_mfma<<<dim3(BB * NH * (LQ / 256)), 512, 0, stream>>>(Qp, Kp, Vt, Aattn);

    GemmBatch go;
    go.e[0] = { Aattn, Bo_r, yr, bo_r, 2, 0 };
    go.e[1] = { Aattn, Bo_i, yi, bo_i, 2, 1 };
    for (int z = 2; z < 6; z++) go.e[z] = go.e[0];
    mfma_cgemm<<<dim3(CH / 128, MM / 256, 2), 512, 0, stream>>>(go);
}

// Round 9
// 456.419 us; speedup vs baseline: 1.3365x; 1.0352x over previous
//
#include <hip/hip_runtime.h>

// Problem constants (fixed by reference setup_inputs)
#define BB 2
#define LQ 2048
#define SK 2048
#define CH 1024
#define NH 16
#define HD 64
#define GK 2048          // packed complex K (= 2*CH)
#define MM 4096          // B*L = B*S
#define ATT_SCALE 0.125f // 1/sqrt(64)

typedef _Float16 f16x8 __attribute__((ext_vector_type(8)));
typedef float f32x4 __attribute__((ext_vector_type(4)));
typedef unsigned short u16x8 __attribute__((ext_vector_type(8)));

__device__ __forceinline__ unsigned short h2u(_Float16 h) {
    union { _Float16 h; unsigned short u; } v; v.h = h; return v.u;
}
__device__ __forceinline__ void gload16(const _Float16* g, unsigned short* l) {
    __builtin_amdgcn_global_load_lds(
        (const __attribute__((address_space(1))) void*)g,
        (__attribute__((address_space(3))) void*)l, 16, 0, 0);
}

// 16-lane all-reduce max via DPP (full-rate VALU, no LDS pipe).
__device__ __forceinline__ float dpp_max16(float x) {
    union { float f; int i; } v, r;
    v.f = x;
    r.i = __builtin_amdgcn_update_dpp(v.i, v.i, 0xB1, 0xF, 0xF, false);  // quad_perm [1,0,3,2]
    v.f = fmaxf(v.f, r.f);
    r.i = __builtin_amdgcn_update_dpp(v.i, v.i, 0x4E, 0xF, 0xF, false);  // quad_perm [2,3,0,1]
    v.f = fmaxf(v.f, r.f);
    r.i = __builtin_amdgcn_update_dpp(v.i, v.i, 0x141, 0xF, 0xF, false); // row_half_mirror
    v.f = fmaxf(v.f, r.f);
    r.i = __builtin_amdgcn_update_dpp(v.i, v.i, 0x140, 0xF, 0xF, false); // row_mirror
    v.f = fmaxf(v.f, r.f);
    return v.f;
}

// XOR-swizzled LDS half-index (T2). Involution; writes and reads both use it.
__device__ __forceinline__ int swzi(int row, int colh, int ldh) {
    return row * ldh + (colh ^ ((row & 7) << 3));
}

// ---------------------------------------------------------------------------
// pack_x: build packed A = [x_r | x_i]  (M, 2048) fp16, row-major.
// Vectorized (float4 x2 read, u16x8 write).
// ---------------------------------------------------------------------------
struct PackXEnt { const float* r; const float* i; _Float16* dst; };
struct PackXBatch { PackXEnt e[2]; };

__global__ __launch_bounds__(256) void pack_x_kernel(PackXBatch b)
{
    PackXEnt e = b.e[blockIdx.z];
    const size_t total8 = (size_t)MM * GK / 8;     // 8-half spans
    for (size_t s = (size_t)blockIdx.x * 256 + threadIdx.x; s < total8;
         s += (size_t)gridDim.x * 256) {
        size_t m = s >> 8;                         // 256 spans per row
        int c8 = (int)(s & 255) * 8;               // half-col (multiple of 8)
        const float* src = (c8 < CH) ? (e.r + m * CH + c8)
                                     : (e.i + m * CH + (c8 - CH));
        float4 a = *(const float4*)(src);
        float4 c = *(const float4*)(src + 4);
        u16x8 o;
        o[0] = h2u((_Float16)a.x); o[1] = h2u((_Float16)a.y);
        o[2] = h2u((_Float16)a.z); o[3] = h2u((_Float16)a.w);
        o[4] = h2u((_Float16)c.x); o[5] = h2u((_Float16)c.y);
        o[6] = h2u((_Float16)c.z); o[7] = h2u((_Float16)c.w);
        *(u16x8*)(e.dst + s * 8) = o;
    }
}

// ---------------------------------------------------------------------------
// pack_w: Bt (N=1024, K=2048) fp16 = transposed packed weights. (unchanged)
// ---------------------------------------------------------------------------
struct PackWEnt { const float* a; const float* b; float signb; _Float16* dst; };
struct PackWBatch { PackWEnt e[8]; };

__global__ __launch_bounds__(256) void pack_w_kernel(PackWBatch bt)
{
    PackWEnt e = bt.e[blockIdx.z];
    const int k0 = blockIdx.x * 32;
    const int n0 = blockIdx.y * 32;
    const float* src = (k0 < CH) ? e.a : e.b;
    const float sign = (k0 < CH) ? 1.f : e.signb;
    const int kk = k0 & (CH - 1);

    __shared__ float sT[32][33];
    const int t = threadIdx.x;
    const int tx = t & 31, ty = t >> 5;

    #pragma unroll
    for (int r = 0; r < 4; r++) {
        int kl = ty + r * 8;
        sT[kl][tx] = src[(size_t)(kk + kl) * CH + n0 + tx] * sign;
    }
    __syncthreads();
    #pragma unroll
    for (int r = 0; r < 4; r++) {
        int nl = ty + r * 8;
        e.dst[(size_t)(n0 + nl) * GK + k0 + tx] = (_Float16)sT[tx][nl];
    }
}

// ---------------------------------------------------------------------------
// fp16 MFMA GEMM, round 13: 2-blocks/CU occupancy push.
//  - 3-slot ring (72 KiB LDS; 2x72=144 <= 160) — counted vmcnt(3) steady
//    state, ring distance 2.
//  - __launch_bounds__(512, 4): 16 waves/CU target -> <=128 combined
//    VGPR+AGPR (was 152). bf reads moved into the j-loop to shrink live
//    B-fragment range so the allocator can meet the cap without spilling.
//  - Mechanism (m114): a co-resident second block fills the sync/stage
//    gaps that hold MfmaUtil at 32% with 1 block/CU.
// 256x128 tile, BK=32, 8 waves (4M x 2N, 64x64/wave), single barrier/K-step.
// Epilogue modes: 0 = head-packed QK fp16; 1 = head-packed V^T; 2 = fp32+bias.
// ---------------------------------------------------------------------------
struct GemmEnt { const _Float16* A; const _Float16* Bt; void* out;
                 const float* bias; int mode; int part; };
struct GemmBatch { GemmEnt e[6]; };

#define NT   (GK / 32)   // 64 K-steps
#define BUFH 12288       // halfs per ring slot: A 256x32 (8192) + B 128x32 (4096)

#define SWZ(x) ((x) ^ ((((x) >> 7) & 3) << 4))

__global__ __launch_bounds__(512, 4) void mfma_cgemm(GemmBatch bt)
{
    GemmEnt e = bt.e[blockIdx.z];
    __shared__ unsigned short lds[3 * BUFH];   // 72 KiB, 3-slot ring

    const int t    = threadIdx.x;
    const int wave = t >> 6;
    const int lane = t & 63;
    const int lm   = lane & 15;
    const int quad = lane >> 4;
    const int wr   = wave >> 1;        // 0..3 -> 64-row M band
    const int wc   = wave & 1;         // 0..1 -> 64-col N band

    const int m0 = blockIdx.y * 256;
    const int n0 = blockIdx.x * 128;

    int srow[2], scol[2];
    #pragma unroll
    for (int L = 0; L < 2; L++) {
        int p = (L * 512 + t) * 16;
        int q = SWZ(p);
        srow[L] = q >> 6;
        scol[L] = (q >> 1) & 31;
    }

    const _Float16* gA = e.A  + (size_t)m0 * GK;
    const _Float16* gB = e.Bt + (size_t)n0 * GK;

    auto stage = [&](int kt, int slot) {
        unsigned short* base = lds + slot * BUFH;
        #pragma unroll
        for (int L = 0; L < 2; L++)
            gload16(gA + (size_t)srow[L] * GK + kt * 32 + scol[L],
                    base + (L * 512 + t) * 8);
        gload16(gB + (size_t)srow[0] * GK + kt * 32 + scol[0],
                base + 8192 + t * 8);
    };

    const int qA    = (wr * 64 + lm) * 64 + quad * 16;
    const int physA = SWZ(qA) >> 1;
    const int qB    = (wc * 64 + lm) * 64 + quad * 16;
    const int physB = (SWZ(qB) >> 1) + 8192;

    f32x4 acc[4][4] = {};

    // prologue: stage tiles 0,1 (slots 0,1); ensure tile 0 landed
    stage(0, 0); stage(1, 1);
    asm volatile("s_waitcnt vmcnt(3)" ::: "memory");

    int rs = 0;        // read slot for kt
    int ss = 2;        // stage slot for kt+2
    for (int kt = 0; kt < NT; ++kt) {
        __builtin_amdgcn_s_barrier();   // staged slot rs visible to all waves

        const unsigned short* buf = lds + rs * BUFH;
        f16x8 af[4];
        #pragma unroll
        for (int i = 0; i < 4; i++)
            af[i] = *(const f16x8*)&buf[physA + i * 512];

        if (kt + 2 < NT) stage(kt + 2, ss);   // slot ss: consumed @ kt-1

        __builtin_amdgcn_s_setprio(1);
        #pragma unroll
        for (int j = 0; j < 4; j++) {
            f16x8 bfj = *(const f16x8*)&buf[physB + j * 512];
            #pragma unroll
            for (int i = 0; i < 4; i++)
                acc[i][j] = __builtin_amdgcn_mfma_f32_16x16x32_f16(
                    af[i], bfj, acc[i][j], 0, 0, 0);
        }
        __builtin_amdgcn_s_setprio(0);

        // counted drain BEFORE next barrier: tile kt+1 (staged 2 iters ago)
        // must be landed; the newest stage (3 loads) stays in flight.
        if (kt + 2 < NT)       asm volatile("s_waitcnt vmcnt(3)" ::: "memory");
        else if (kt == NT - 2) asm volatile("s_waitcnt vmcnt(0)" ::: "memory");

        rs = (rs == 2) ? 0 : rs + 1;
        ss = (ss == 2) ? 0 : ss + 1;
    }

    const int mode = e.mode, part = e.part;
    #pragma unroll
    for (int j = 0; j < 4; j++) {
        int gcol = n0 + wc * 64 + j * 16 + lm;
        float bv = (mode == 2 && e.bias) ? e.bias[gcol] : 0.f;
        #pragma unroll
        for (int i = 0; i < 4; i++) {
            int growb = m0 + wr * 64 + i * 16 + quad * 4;
            #pragma unroll
            for (int reg = 0; reg < 4; reg++) {
                int grow = growb + reg;
                float v = acc[i][j][reg];
                if (mode == 2) {
                    ((float*)e.out)[(size_t)grow * CH + gcol] = v + bv;
                } else {
                    int b = grow >> 11, l = grow & 2047;
                    int h = gcol >> 6, dd = gcol & 63;
                    size_t off;
                    if (mode == 0)
                        off = (((size_t)(b * NH + h)) * LQ + l) * 128 + part * 64 + dd;
                    else
                        off = (((size_t)(b * NH + h)) * 128 + part * 64 + dd) * SK + l;
                    ((_Float16*)e.out)[off] = (_Float16)v;
                }
            }
        }
    }
}

// ---------------------------------------------------------------------------
// MFMA flash attention (round-10 structure, unchanged — verified improvement):
// 256-row Q-tile, 512 thr / 8 waves / 1 block per CU; Q direct to regs;
// XCD-bijective swizzle (4 K/V streams per XCD); T2 LDS swizzle; T13
// wave-uniform defer-max.
// LDS (halfs): sP 256x64 @0, sK 64x128 @16384, sV 144x64 @24576 (67584 B).
// ---------------------------------------------------------------------------
__global__ __launch_bounds__(512, 2) void attn_mfma(
    const _Float16* __restrict__ Qp, const _Float16* __restrict__ Kp,
    const _Float16* __restrict__ Vt, _Float16* __restrict__ Aattn)
{
    __shared__ unsigned short lds[33792];
    unsigned short* sP = lds;            // 256 x 64 (swz, ld 64)
    unsigned short* sK = lds + 16384;    // 64 x 128 (swz, ld 128)
    unsigned short* sV = lds + 24576;    // 144 x 64 (swz, ld 64)

    const int t    = threadIdx.x;
    const int w    = t >> 6;             // 0..7
    const int lane = t & 63;
    const int lm   = lane & 15;
    const int quad = lane >> 4;

    const int bx  = blockIdx.x;
    const int bid = (bx & 7) * 32 + (bx >> 3);
    const int mt  = bid & 7;             // Q tile (256 rows), 0..7
    const int h   = (bid >> 3) & 15;
    const int b   = bid >> 7;

    const _Float16* qb = Qp + (((size_t)(b * NH + h)) * LQ + (size_t)mt * 256) * 128;
    const _Float16* kb = Kp + ((size_t)(b * NH + h)) * SK * 128;
    const _Float16* vb = Vt + ((size_t)(b * NH + h)) * 128 * SK;

    // ones tail rows of sV (rows 128..143): the l-accumulator trick
    for (int idx = t; idx < 16 * 64; idx += 512) {
        int row = 128 + (idx >> 6);
        int col = idx & 63;
        sV[row * 64 + (col ^ ((row & 7) << 3))] = 0x3C00;   // fp16 1.0
    }

    // Q -> A-frags DIRECTLY from global (held for whole kernel)
    f16x8 qf[2][4];
    #pragma unroll
    for (int i = 0; i < 2; i++)
        #pragma unroll
        for (int kk = 0; kk < 4; kk++)
            qf[i][kk] = *(const f16x8*)(qb + (size_t)(w * 32 + i * 16 + lm) * 128
                                           + kk * 32 + quad * 8);

    // preload K/V tile 0 into regs
    u16x8 kreg[2], vreg[2];
    #pragma unroll
    for (int p = 0; p < 2; p++) {
        int idx = p * 512 + t;
        int r = idx >> 4, sg = idx & 15;
        kreg[p] = *(const u16x8*)(kb + (size_t)r * 128 + sg * 8);
        int rv = idx >> 3, sv = idx & 7;
        vreg[p] = *(const u16x8*)(vb + (size_t)rv * SK + sv * 8);
    }

    f32x4 oacc[2][9] = {};
    float m_st[2][4];
    #pragma unroll
    for (int i = 0; i < 2; i++)
        #pragma unroll
        for (int r = 0; r < 4; r++) m_st[i][r] = -1e30f;

    const float SC2 = ATT_SCALE * 1.44269504f;   // exp2 domain

    for (int it = 0; it < SK / 64; ++it) {
        __syncthreads();                         // WAR: prev PV reads vs staging
        #pragma unroll
        for (int p = 0; p < 2; p++) {
            int idx = p * 512 + t;
            int r = idx >> 4, sg = idx & 15;
            *(u16x8*)&sK[swzi(r, sg * 8, 128)] = kreg[p];
            int rv = idx >> 3, sv = idx & 7;
            *(u16x8*)&sV[swzi(rv, sv * 8, 64)] = vreg[p];
        }
        __syncthreads();

        if (it + 1 < SK / 64) {                  // prefetch next tile
            int s0n = (it + 1) * 64;
            #pragma unroll
            for (int p = 0; p < 2; p++) {
                int idx = p * 512 + t;
                int r = idx >> 4, sg = idx & 15;
                kreg[p] = *(const u16x8*)(kb + (size_t)(s0n + r) * 128 + sg * 8);
                int rv = idx >> 3, sv = idx & 7;
                vreg[p] = *(const u16x8*)(vb + (size_t)rv * SK + s0n + sv * 8);
            }
        }

        // ---- QK^T: wave rows 32 x cols 64, k = 128 (Q from regs) ----
        f32x4 sacc[2][4] = {};
        #pragma unroll
        for (int kk = 0; kk < 4; kk++) {
            f16x8 bfr[4];
            #pragma unroll
            for (int j = 0; j < 4; j++)
                bfr[j] = *(const f16x8*)&sK[swzi(j * 16 + lm, kk * 32 + quad * 8, 128)];
            #pragma unroll
            for (int i = 0; i < 2; i++)
                #pragma unroll
                for (int j = 0; j < 4; j++)
                    sacc[i][j] = __builtin_amdgcn_mfma_f32_16x16x32_f16(
                        qf[i][kk], bfr[j], sacc[i][j], 0, 0, 0);
        }

        // ---- online softmax (T13, wave-uniform rare-rescale) ----
        float mx[2][4];
        #pragma unroll
        for (int i = 0; i < 2; i++)
            #pragma unroll
            for (int r = 0; r < 4; r++) {
                float m4 = fmaxf(fmaxf(sacc[i][0][r], sacc[i][1][r]),
                                 fmaxf(sacc[i][2][r], sacc[i][3][r]));
                mx[i][r] = dpp_max16(m4) * SC2;
            }
        int need = 0;
        #pragma unroll
        for (int i = 0; i < 2; i++)
            #pragma unroll
            for (int r = 0; r < 4; r++)
                need |= (mx[i][r] > m_st[i][r] + 8.0f) ? 1 : 0;
        if (__any(need)) {
            #pragma unroll
            for (int i = 0; i < 2; i++)
                #pragma unroll
                for (int r = 0; r < 4; r++) {
                    float mnew = fmaxf(m_st[i][r], mx[i][r]);
                    float al = exp2f(m_st[i][r] - mnew);
                    m_st[i][r] = mnew;
                    #pragma unroll
                    for (int j2 = 0; j2 < 9; j2++)
                        oacc[i][j2][r] *= al;
                }
        }
        #pragma unroll
        for (int i = 0; i < 2; i++)
            #pragma unroll
            for (int r = 0; r < 4; r++) {
                float mcur = m_st[i][r];
                int rowp = w * 32 + i * 16 + quad * 4 + r;
                #pragma unroll
                for (int j = 0; j < 4; j++) {
                    float p = exp2f(sacc[i][j][r] * SC2 - mcur);
                    sP[swzi(rowp, j * 16 + lm, 64)] = h2u((_Float16)p);
                }
            }

        // ---- PV: O[m][d] += P[m][s] * Vt[d][s]; j2=8 (ones rows) -> l ----
        #pragma unroll
        for (int kk = 0; kk < 2; kk++) {
            f16x8 pf[2], vf[9];
            #pragma unroll
            for (int i = 0; i < 2; i++)
                pf[i] = *(const f16x8*)&sP[swzi(w * 32 + i * 16 + lm, kk * 32 + quad * 8, 64)];
            #pragma unroll
            for (int j2 = 0; j2 < 9; j2++)
                vf[j2] = *(const f16x8*)&sV[swzi(j2 * 16 + lm, kk * 32 + quad * 8, 64)];
            #pragma unroll
            for (int i = 0; i < 2; i++)
                #pragma unroll
                for (int j2 = 0; j2 < 9; j2++)
                    oacc[i][j2] = __builtin_amdgcn_mfma_f32_16x16x32_f16(
                        pf[i], vf[j2], oacc[i][j2], 0, 0, 0);
        }
    }

    // ---- epilogue: l = oacc[i][8][r] (valid in every lane); normalize ----
    #pragma unroll
    for (int i = 0; i < 2; i++) {
        #pragma unroll
        for (int r = 0; r < 4; r++) {
            float inv = 1.f / oacc[i][8][r];
            int ml = w * 32 + i * 16 + quad * 4 + r;
            size_t row = (size_t)b * LQ + (size_t)mt * 256 + ml;
            #pragma unroll
            for (int j2 = 0; j2 < 8; j2++) {
                int d = j2 * 16 + lm;
                int dcol = (d < HD) ? h * HD + d : CH + h * HD + (d - HD);
                Aattn[row * GK + dcol] = (_Float16)(oacc[i][j2][r] * inv);
            }
        }
    }
}

// ---------------------------------------------------------------------------
extern "C" void kernel_launch(void* const* d_in, const int* in_sizes, int n_in,
                              void* d_out, int out_size, void* d_ws, size_t ws_size,
                              hipStream_t stream)
{
    const float* in_r = (const float*)d_in[0];
    const float* in_i = (const float*)d_in[1];
    const float* cx_r = (const float*)d_in[2];
    const float* cx_i = (const float*)d_in[3];
    const float* wq_r = (const float*)d_in[4];
    const float* wq_i = (const float*)d_in[5];
    const float* wk_r = (const float*)d_in[6];
    const float* wk_i = (const float*)d_in[7];
    const float* wv_r = (const float*)d_in[8];
    const float* wv_i = (const float*)d_in[9];
    const float* wo_r = (const float*)d_in[10];
    const float* wo_i = (const float*)d_in[11];
    const float* bo_r = (const float*)d_in[12];
    const float* bo_i = (const float*)d_in[13];

    _Float16* ws = (_Float16*)d_ws;
    const size_t A_ELEMS = (size_t)MM * GK;
    const size_t B_ELEMS = (size_t)CH * GK;
    const size_t H_ELEMS = (size_t)BB * NH * LQ * 128;

    _Float16* Ain   = ws;
    _Float16* Aattn = ws;                          // alias (Ain dead after qkv GEMM)
    _Float16* Actx  = Ain + A_ELEMS;
    _Float16* Bp    = Actx + A_ELEMS;
    _Float16* Qp    = Bp + 8 * B_ELEMS;
    _Float16* Kp    = Qp + H_ELEMS;
    _Float16* Vt    = Kp + H_ELEMS;

    _Float16* Bq_r = Bp + 0 * B_ELEMS;
    _Float16* Bq_i = Bp + 1 * B_ELEMS;
    _Float16* Bk_r = Bp + 2 * B_ELEMS;
    _Float16* Bk_i = Bp + 3 * B_ELEMS;
    _Float16* Bv_r = Bp + 4 * B_ELEMS;
    _Float16* Bv_i = Bp + 5 * B_ELEMS;
    _Float16* Bo_r = Bp + 6 * B_ELEMS;
    _Float16* Bo_i = Bp + 7 * B_ELEMS;

    float* out = (float*)d_out;
    float* yr = out;
    float* yi = out + (size_t)MM * CH;

    PackXBatch px;
    px.e[0] = { in_r, in_i, Ain  };
    px.e[1] = { cx_r, cx_i, Actx };
    pack_x_kernel<<<dim3(2048, 1, 2), 256, 0, stream>>>(px);

    PackWBatch pw;
    pw.e[0] = { wq_r, wq_i, -1.f, Bq_r };
    pw.e[1] = { wq_i, wq_r,  1.f, Bq_i };
    pw.e[2] = { wk_r, wk_i, -1.f, Bk_r };
    pw.e[3] = { wk_i, wk_r,  1.f, Bk_i };
    pw.e[4] = { wv_r, wv_i, -1.f, Bv_r };
    pw.e[5] = { wv_i, wv_r,  1.f, Bv_i };
    pw.e[6] = { wo_r, wo_i, -1.f, Bo_r };
    pw.e[7] = { wo_i, wo_r,  1.f, Bo_i };
    pack_w_kernel<<<dim3(GK / 32, CH / 32, 8), 256, 0, stream>>>(pw);

    GemmBatch gq;
    gq.e[0] = { Ain,  Bq_r, Qp, nullptr, 0, 0 };
    gq.e[1] = { Ain,  Bq_i, Qp, nullptr, 0, 1 };
    gq.e[2] = { Actx, Bk_r, Kp, nullptr, 0, 0 };
    gq.e[3] = { Actx, Bk_i, Kp, nullptr, 0, 1 };
    gq.e[4] = { Actx, Bv_r, Vt, nullptr, 1, 0 };
    gq.e[5] = { Actx, Bv_i, Vt, nullptr, 1, 1 };
    mfma_cgemm<<<dim3(CH / 128, MM / 256, 6), 512, 0, stream>>>(gq);

    attn_mfma<<<dim3(BB * NH * (LQ / 256)), 512, 0, stream>>>(Qp, Kp, Vt, Aattn);

    GemmBatch go;
    go.e[0] = { Aattn, Bo_r, yr, bo_r, 2, 0 };
    go.e[1] = { Aattn, Bo_i, yi, bo_i, 2, 1 };
    for (int z = 2; z < 6; z++) go.e[z] = go.e[0];
    mfma_cgemm<<<dim3(CH / 128, MM / 256, 2), 512, 0, stream>>>(go);
}